// Round 3
// baseline (529.438 us; speedup 1.0000x reference)
//
#include <hip/hip_runtime.h>

// Problem constants
#define BATCH   4096
#define NF      39          // num_field
#define ED      16          // embedding size
#define IN_DIM  624         // NF*ED
#define DW      400
#define BN_EPS  1e-5f
#define KTOT    2496        // CIN K = 39 m * 64 h (h padded)
#define NKSG    78          // KTOT/32
#define AK1     640         // padded deep K for layer 1 input (624 -> 640)
#define NKS1    20          // AK1/32
#define NKS2    13          // 400 -> 416 padded

typedef __attribute__((ext_vector_type(8))) short short8;
typedef __attribute__((ext_vector_type(4))) float f32x4;
typedef unsigned short u16;

__device__ inline unsigned pack2_trunc(float a, float b) {
  return (__float_as_uint(a) >> 16) | (__float_as_uint(b) & 0xffff0000u);
}
__device__ inline unsigned bf16_rne(float f) {
  unsigned u = __float_as_uint(f);
  u += 0x7fff + ((u >> 16) & 1);
  return u >> 16;
}
__device__ inline float bf2f(u16 v) { return __uint_as_float((unsigned)v << 16); }

// ---------------------------------------------------------------------------
// Zero small accumulators (ws is poisoned 0xAA before every launch)
// ---------------------------------------------------------------------------
__global__ __launch_bounds__(256) void k_zero(float* __restrict__ p, int n) {
  int i = blockIdx.x * 256 + threadIdx.x;
  if (i < n) p[i] = 0.f;
}

// ---------------------------------------------------------------------------
// Kernel 1: embedding gather -> flatb[B][640] bf16 (zero-padded), + linear part
// ---------------------------------------------------------------------------
__global__ __launch_bounds__(256) void k_gather(const int* __restrict__ idx,
    const float* __restrict__ emb, const float* __restrict__ lw,
    const float* __restrict__ lb, u16* __restrict__ flatb,
    float* __restrict__ lp) {
  int b = blockIdx.x, t = threadIdx.x;
  __shared__ int si[NF];
  if (t < NF) si[t] = idx[b * NF + t];
  __syncthreads();
  float acc = 0.f;
#pragma unroll
  for (int i = 0; i < 3; i++) {
    int e = t + i * 256;
    if (e < IN_DIM) {
      float v = emb[(size_t)si[e >> 4] * ED + (e & 15)];
      flatb[(size_t)b * AK1 + e] = (u16)bf16_rne(v);
      acc = fmaf(v, lw[e], acc);
    } else if (e < AK1) {
      flatb[(size_t)b * AK1 + e] = 0;
    }
  }
#pragma unroll
  for (int k = 1; k < 64; k <<= 1) acc += __shfl_xor(acc, k);
  __shared__ float r4[4];
  if ((t & 63) == 0) r4[t >> 6] = acc;
  __syncthreads();
  if (t == 0) lp[b] = r4[0] + r4[1] + r4[2] + r4[3] + lb[0];
}

// ---------------------------------------------------------------------------
// Weight pre-pack into B-fragment layout: wp[ksg][col][kk] bf16,
// lane (nl=col%16, q) reads 8 contiguous at col*32 + q*8.
// CIN: k = ksg*32+kk -> h=k&63, m=k>>6.  Deep: k plain row index.
// ---------------------------------------------------------------------------
__global__ __launch_bounds__(256) void k_prep(const float* __restrict__ w1,
    const float* __restrict__ w2, const float* __restrict__ dw1,
    const float* __restrict__ dw2, u16* __restrict__ wp1, u16* __restrict__ wp2,
    u16* __restrict__ wpd1, u16* __restrict__ wpd2) {
  const int CIN_E = NKSG * 128 * 32;   // 319488
  const int D1_E  = NKS1 * 400 * 32;   // 256000
  const int D2_E  = NKS2 * 400 * 32;   // 166400
  int e = blockIdx.x * 256 + threadIdx.x;
  if (e < CIN_E) {
    int ksg = e >> 12, r = e & 4095, n = r >> 5, kk = r & 31;
    int k = ksg * 32 + kk, h = k & 63, m = k >> 6;
    float v1 = (h < NF) ? w1[(size_t)n * (NF * NF) + h * NF + m] : 0.f;
    float v2 = w2[(size_t)n * (64 * NF) + h * NF + m];
    wp1[e] = (u16)bf16_rne(v1);
    wp2[e] = (u16)bf16_rne(v2);
  } else if (e < CIN_E + D1_E) {
    int e2 = e - CIN_E;
    int ksg = e2 / 12800, r = e2 - ksg * 12800, col = r >> 5, kk = r & 31;
    int k = ksg * 32 + kk;
    wpd1[e2] = (k < IN_DIM) ? (u16)bf16_rne(dw1[(size_t)k * DW + col]) : 0;
  } else if (e < CIN_E + D1_E + D2_E) {
    int e2 = e - CIN_E - D1_E;
    int ksg = e2 / 12800, r = e2 - ksg * 12800, col = r >> 5, kk = r & 31;
    int k = ksg * 32 + kk;
    wpd2[e2] = (k < DW) ? (u16)bf16_rne(dw2[(size_t)k * DW + col]) : 0;
  }
}

// ---------------------------------------------------------------------------
// CIN via MFMA (unchanged structure; flat is now bf16).
// ---------------------------------------------------------------------------
template <bool LAY2>
__global__ __launch_bounds__(256, 2) void k_cin_mfma(
    const u16* __restrict__ flatb, const u16* __restrict__ nxtg,
    const u16* __restrict__ wp, const float* __restrict__ bias,
    u16* __restrict__ nxt_out, float* __restrict__ res) {
  int t = threadIdx.x;
  int w = t >> 6, lane = t & 63;
  int nl = lane & 15, q = lane >> 4;
  int d = nl;
  int b0 = blockIdx.x * 16 + w * 4;

  unsigned nxr[4][2][4];
  if (LAY2) {
#pragma unroll
    for (int si = 0; si < 4; si++)
#pragma unroll
      for (int ks = 0; ks < 2; ks++) {
        uint4 v = *(const uint4*)(nxtg +
            (((size_t)(b0 + si) * 16 + d) * 64 + ks * 32 + q * 8));
        nxr[si][ks][0] = v.x; nxr[si][ks][1] = v.y;
        nxr[si][ks][2] = v.z; nxr[si][ks][3] = v.w;
      }
  } else {
#pragma unroll
    for (int si = 0; si < 4; si++)
#pragma unroll
      for (int ks = 0; ks < 2; ks++)
#pragma unroll
        for (int w4 = 0; w4 < 4; w4++) {
          int h0 = ks * 32 + q * 8 + 2 * w4;
          int h1 = h0 + 1;
          unsigned u0 = (h0 < NF) ? flatb[(size_t)(b0 + si) * AK1 + h0 * 16 + d] : 0;
          unsigned u1 = (h1 < NF) ? flatb[(size_t)(b0 + si) * AK1 + h1 * 16 + d] : 0;
          nxr[si][ks][w4] = u0 | (u1 << 16);
        }
  }

  f32x4 acc[4][8];
#pragma unroll
  for (int si = 0; si < 4; si++)
#pragma unroll
    for (int nt = 0; nt < 8; nt++) acc[si][nt] = (f32x4){0.f, 0.f, 0.f, 0.f};

  for (int m = 0; m < NF; m++) {
    float xv[4];
#pragma unroll
    for (int si = 0; si < 4; si++)
      xv[si] = bf2f(flatb[(size_t)(b0 + si) * AK1 + m * 16 + d]);
#pragma unroll
    for (int ks = 0; ks < 2; ks++) {
      int ksg = m * 2 + ks;
      const u16* wb = wp + (size_t)ksg * 4096 + nl * 32 + q * 8;
      short8 bfr[8];
#pragma unroll
      for (int nt = 0; nt < 8; nt++)
        bfr[nt] = *(const short8*)(wb + nt * 512);
      short8 afr[4];
#pragma unroll
      for (int si = 0; si < 4; si++) {
        union { unsigned u[4]; short8 s; } a;
#pragma unroll
        for (int w4 = 0; w4 < 4; w4++) {
          unsigned u = nxr[si][ks][w4];
          float lo = __uint_as_float(u << 16) * xv[si];
          float hi = __uint_as_float(u & 0xffff0000u) * xv[si];
          a.u[w4] = pack2_trunc(lo, hi);
        }
        afr[si] = a.s;
      }
#pragma unroll
      for (int nt = 0; nt < 8; nt++)
#pragma unroll
        for (int si = 0; si < 4; si++)
          acc[si][nt] = __builtin_amdgcn_mfma_f32_16x16x32_bf16(
              afr[si], bfr[nt], acc[si][nt], 0, 0, 0);
    }
  }

#pragma unroll
  for (int si = 0; si < 4; si++) {
    int b = b0 + si;
#pragma unroll
    for (int nt = 0; nt < 8; nt++) {
      int o = nt * 16 + nl;
      float bi = bias[o];
      if (!LAY2 && nt < 4) {
#pragma unroll
        for (int r = 0; r < 4; r++) {
          float v = fmaxf(acc[si][nt][r] + bi, 0.f);
          nxt_out[((size_t)b * 16 + q * 4 + r) * 64 + o] = (u16)bf16_rne(v);
        }
      } else {
        float s = 0.f;
#pragma unroll
        for (int r = 0; r < 4; r++) s += fmaxf(acc[si][nt][r] + bi, 0.f);
        s += __shfl_xor(s, 16);
        s += __shfl_xor(s, 32);
        if (q == 0) {
          int ri = LAY2 ? (64 + o) : (o - 64);
          res[(size_t)b * 192 + ri] = s;
        }
      }
    }
  }
}

// ---------------------------------------------------------------------------
// Deep-tower GEMM via MFMA. C[M][400] = op(A)[M][K] * W + bias, where
// op(A) = A (bf16, BN_A=false) or relu(bn(A_f32)) cast to bf16 (BN_A=true).
// Fused BN stats: per-column sum / sumsq of C (pre-BN) -> global atomics.
// Grid: (M/64, 5). Wave = 16 rows x 80 cols (5 n-tiles), no LDS staging.
// ---------------------------------------------------------------------------
template <bool BN_A, int NKS, int KREAL>
__global__ __launch_bounds__(256) void k_gemm_mfma(
    const u16* __restrict__ Abf, const float* __restrict__ Af32,
    const u16* __restrict__ wp, const float* __restrict__ bias,
    const float* __restrict__ bnS, const float* __restrict__ bnSh,
    float* __restrict__ C, float* __restrict__ gs, float* __restrict__ gs2) {
  __shared__ float ls[160];
  int t = threadIdx.x;
  if (t < 160) ls[t] = 0.f;
  __syncthreads();
  int w = t >> 6, lane = t & 63;
  int nl = lane & 15, q = lane >> 4;
  int row = blockIdx.x * 64 + w * 16 + nl;
  int c0 = blockIdx.y * 80;
  f32x4 acc[5];
#pragma unroll
  for (int nt = 0; nt < 5; nt++) acc[nt] = (f32x4){0.f, 0.f, 0.f, 0.f};

  for (int ksg = 0; ksg < NKS; ksg++) {
    int kb = ksg * 32 + q * 8;
    short8 afr;
    if (!BN_A) {
      afr = *(const short8*)(Abf + (size_t)row * (NKS * 32) + kb);
    } else {
      if (kb + 8 <= KREAL) {
        const float* ap = Af32 + (size_t)row * KREAL + kb;
        float4 f0 = *(const float4*)ap;
        float4 f1 = *(const float4*)(ap + 4);
        union { unsigned u[4]; short8 s; } a;
        float v0 = fmaxf(fmaf(f0.x, bnS[kb + 0], bnSh[kb + 0]), 0.f);
        float v1 = fmaxf(fmaf(f0.y, bnS[kb + 1], bnSh[kb + 1]), 0.f);
        float v2 = fmaxf(fmaf(f0.z, bnS[kb + 2], bnSh[kb + 2]), 0.f);
        float v3 = fmaxf(fmaf(f0.w, bnS[kb + 3], bnSh[kb + 3]), 0.f);
        float v4 = fmaxf(fmaf(f1.x, bnS[kb + 4], bnSh[kb + 4]), 0.f);
        float v5 = fmaxf(fmaf(f1.y, bnS[kb + 5], bnSh[kb + 5]), 0.f);
        float v6 = fmaxf(fmaf(f1.z, bnS[kb + 6], bnSh[kb + 6]), 0.f);
        float v7 = fmaxf(fmaf(f1.w, bnS[kb + 7], bnSh[kb + 7]), 0.f);
        a.u[0] = bf16_rne(v0) | (bf16_rne(v1) << 16);
        a.u[1] = bf16_rne(v2) | (bf16_rne(v3) << 16);
        a.u[2] = bf16_rne(v4) | (bf16_rne(v5) << 16);
        a.u[3] = bf16_rne(v6) | (bf16_rne(v7) << 16);
        afr = a.s;
      } else {
        union { unsigned u[4]; short8 s; } a;
        a.u[0] = a.u[1] = a.u[2] = a.u[3] = 0;
        afr = a.s;
      }
    }
    const u16* wb = wp + (size_t)ksg * (400 * 32) + (size_t)(c0 + nl) * 32 + q * 8;
#pragma unroll
    for (int nt = 0; nt < 5; nt++) {
      short8 bfr = *(const short8*)(wb + nt * 512);
      acc[nt] = __builtin_amdgcn_mfma_f32_16x16x32_bf16(afr, bfr, acc[nt], 0, 0, 0);
    }
  }

  int rbase = blockIdx.x * 64 + w * 16 + q * 4;
#pragma unroll
  for (int nt = 0; nt < 5; nt++) {
    int col = c0 + nt * 16 + nl;
    float bi = bias[col];
    float s = 0.f, s2 = 0.f;
#pragma unroll
    for (int r = 0; r < 4; r++) {
      float v = acc[nt][r] + bi;
      C[(size_t)(rbase + r) * DW + col] = v;
      s += v; s2 = fmaf(v, v, s2);
    }
    s += __shfl_xor(s, 16); s2 += __shfl_xor(s2, 16);
    s += __shfl_xor(s, 32); s2 += __shfl_xor(s2, 32);
    if (q == 0) {
      atomicAdd(&ls[nt * 16 + nl], s);
      atomicAdd(&ls[80 + nt * 16 + nl], s2);
    }
  }
  __syncthreads();
  if (t < 80)       atomicAdd(&gs[c0 + t], ls[t]);
  else if (t < 160) atomicAdd(&gs2[c0 + t - 80], ls[t]);
}

// ---------------------------------------------------------------------------
// BN finalize: (sum, sumsq) -> fused scale/shift
// ---------------------------------------------------------------------------
__global__ __launch_bounds__(256) void k_bnfin(const float* __restrict__ gs,
    const float* __restrict__ gs2, const float* __restrict__ g,
    const float* __restrict__ bt, float* __restrict__ sc, float* __restrict__ sh) {
  int c = blockIdx.x * 256 + threadIdx.x;
  if (c >= DW) return;
  float m = gs[c] * (1.f / BATCH);
  float var = gs2[c] * (1.f / BATCH) - m * m;
  float scl = g[c] * rsqrtf(var + BN_EPS);
  sc[c] = scl;
  sh[c] = bt[c] - m * scl;
}

// ---------------------------------------------------------------------------
// Final concat + dot
// ---------------------------------------------------------------------------
__global__ __launch_bounds__(256) void k_final(const float* __restrict__ lp,
    const float* __restrict__ res, const float* __restrict__ y2,
    const float* __restrict__ sc2, const float* __restrict__ sh2,
    const float* __restrict__ ow, const float* __restrict__ ob,
    float* __restrict__ out) {
  int t = threadIdx.x;
  int lane = t & 63, w = t >> 6;
  int b = blockIdx.x * 4 + w;
  float acc = 0.f;
  for (int j = lane; j < 593; j += 64) {
    float v;
    if (j == 0)       v = lp[b];
    else if (j < 193) v = res[(size_t)b * 192 + (j - 1)];
    else {
      int c = j - 193;
      v = fmaxf(fmaf(y2[(size_t)b * DW + c], sc2[c], sh2[c]), 0.f);
    }
    acc = fmaf(v, ow[j], acc);
  }
#pragma unroll
  for (int k = 1; k < 64; k <<= 1) acc += __shfl_xor(acc, k);
  if (lane == 0) out[b] = acc + ob[0];
}

// ---------------------------------------------------------------------------
extern "C" void kernel_launch(void* const* d_in, const int* in_sizes, int n_in,
                              void* d_out, int out_size, void* d_ws, size_t ws_size,
                              hipStream_t stream) {
  const int*   feat_index = (const int*)d_in[0];
  const float* emb = (const float*)d_in[2];
  const float* lw  = (const float*)d_in[3];
  const float* lb  = (const float*)d_in[4];
  const float* w1  = (const float*)d_in[5];
  const float* b1  = (const float*)d_in[6];
  const float* w2  = (const float*)d_in[7];
  const float* b2  = (const float*)d_in[8];
  const float* dw1 = (const float*)d_in[9];
  const float* db1 = (const float*)d_in[10];
  const float* g1  = (const float*)d_in[11];
  const float* bb1 = (const float*)d_in[12];
  const float* dw2 = (const float*)d_in[13];
  const float* db2 = (const float*)d_in[14];
  const float* g2  = (const float*)d_in[15];
  const float* bb2 = (const float*)d_in[16];
  const float* ow  = (const float*)d_in[17];
  const float* ob  = (const float*)d_in[18];

  float* ws   = (float*)d_ws;
  u16*  flatb = (u16*)ws;                  // 4096*640 bf16 = 1,310,720 f
  float* y1   = ws + 1310720;              // 4096*400 = 1,638,400 f
  float* res  = ws + 2949120;              // 4096*192 =   786,432 f
  float* lp   = ws + 3735552;              // 4096
  float* bn1s = ws + 3739648;              // 400
  float* bn1b = bn1s + 400;
  float* bn2s = bn1b + 400;
  float* bn2b = bn2s + 400;
  float* gA   = ws + 3741248;              // 400 sum
  float* gA2  = gA + 400;                  // 400 sumsq
  float* gB   = gA2 + 400;
  float* gB2  = gB + 400;                  // gstat block: 1600 total
  u16*  nxtg  = (u16*)(ws + 3742848);      // 4096*16*64 bf16 = 2,097,152 f
  float* y2   = ws + 3742848;              // alias nxtg (dead after cin2)
  u16*  wp1   = (u16*)(ws + 5840000);      // 319,488 bf16 = 159,744 f
  u16*  wp2   = (u16*)(ws + 5999744);      // 159,744 f
  u16*  wpd1  = (u16*)(ws + 6159488);      // 256,000 bf16 = 128,000 f
  u16*  wpd2  = (u16*)(ws + 6287488);      // 166,400 bf16 = 83,200 f -> 6,370,688 f (25.5 MB)
  float* out  = (float*)d_out;

  const int PREP_E = NKSG * 128 * 32 + NKS1 * 400 * 32 + NKS2 * 400 * 32;

  k_zero<<<7, 256, 0, stream>>>(gA, 1600);
  k_gather<<<BATCH, 256, 0, stream>>>(feat_index, emb, lw, lb, flatb, lp);
  k_prep<<<(PREP_E + 255) / 256, 256, 0, stream>>>(w1, w2, dw1, dw2, wp1, wp2, wpd1, wpd2);
  k_cin_mfma<false><<<BATCH / 16, 256, 0, stream>>>(flatb, nullptr, wp1, b1, nxtg, res);
  k_cin_mfma<true><<<BATCH / 16, 256, 0, stream>>>(flatb, nxtg, wp2, b2, nullptr, res);
  k_gemm_mfma<false, NKS1, IN_DIM><<<dim3(BATCH / 64, 5), 256, 0, stream>>>(
      flatb, nullptr, wpd1, db1, nullptr, nullptr, y1, gA, gA2);
  k_bnfin<<<2, 256, 0, stream>>>(gA, gA2, g1, bb1, bn1s, bn1b);
  k_gemm_mfma<true, NKS2, DW><<<dim3(BATCH / 64, 5), 256, 0, stream>>>(
      nullptr, y1, wpd2, db2, bn1s, bn1b, y2, gB, gB2);
  k_bnfin<<<2, 256, 0, stream>>>(gB, gB2, g2, bb2, bn2s, bn2b);
  k_final<<<BATCH / 4, 256, 0, stream>>>(lp, res, y2, bn2s, bn2b, ow, ob, out);
}

// Round 4
// 280.419 us; speedup vs baseline: 1.8880x; 1.8880x over previous
//
#include <hip/hip_runtime.h>

// Problem constants
#define BATCH   4096
#define NF      39          // num_field
#define ED      16          // embedding size
#define IN_DIM  624         // NF*ED
#define DW      400
#define BN_EPS  1e-5f
#define KTOT    2496        // CIN K = 39 m * 64 h (h padded)
#define NKSG    78          // KTOT/32
#define AK1     640         // padded deep K for layer 1 input (624 -> 640)
#define NKS1    20          // AK1/32
#define NKS2    13          // 400 -> 416 padded

typedef __attribute__((ext_vector_type(8))) short short8;
typedef __attribute__((ext_vector_type(4))) float f32x4;
typedef unsigned short u16;

__device__ inline unsigned pack2_trunc(float a, float b) {
  return (__float_as_uint(a) >> 16) | (__float_as_uint(b) & 0xffff0000u);
}
__device__ inline unsigned bf16_rne(float f) {
  unsigned u = __float_as_uint(f);
  u += 0x7fff + ((u >> 16) & 1);
  return u >> 16;
}
__device__ inline float bf2f(u16 v) { return __uint_as_float((unsigned)v << 16); }

// ---------------------------------------------------------------------------
// Kernel 1: embedding gather -> flatb[B][640] bf16 (zero-padded), + linear part
// ---------------------------------------------------------------------------
__global__ __launch_bounds__(256) void k_gather(const int* __restrict__ idx,
    const float* __restrict__ emb, const float* __restrict__ lw,
    const float* __restrict__ lb, u16* __restrict__ flatb,
    float* __restrict__ lp) {
  int b = blockIdx.x, t = threadIdx.x;
  __shared__ int si[NF];
  if (t < NF) si[t] = idx[b * NF + t];
  __syncthreads();
  float acc = 0.f;
#pragma unroll
  for (int i = 0; i < 3; i++) {
    int e = t + i * 256;
    if (e < IN_DIM) {
      float v = emb[(size_t)si[e >> 4] * ED + (e & 15)];
      flatb[(size_t)b * AK1 + e] = (u16)bf16_rne(v);
      acc = fmaf(v, lw[e], acc);
    } else if (e < AK1) {
      flatb[(size_t)b * AK1 + e] = 0;
    }
  }
#pragma unroll
  for (int k = 1; k < 64; k <<= 1) acc += __shfl_xor(acc, k);
  __shared__ float r4[4];
  if ((t & 63) == 0) r4[t >> 6] = acc;
  __syncthreads();
  if (t == 0) lp[b] = r4[0] + r4[1] + r4[2] + r4[3] + lb[0];
}

// ---------------------------------------------------------------------------
// Weight pre-pack into B-fragment layout + zero the BN stat accumulators.
// ---------------------------------------------------------------------------
__global__ __launch_bounds__(256) void k_prep(const float* __restrict__ w1,
    const float* __restrict__ w2, const float* __restrict__ dw1,
    const float* __restrict__ dw2, u16* __restrict__ wp1, u16* __restrict__ wp2,
    u16* __restrict__ wpd1, u16* __restrict__ wpd2, float* __restrict__ gstat) {
  const int CIN_E = NKSG * 128 * 32;   // 319488
  const int D1_E  = NKS1 * 400 * 32;   // 256000
  const int D2_E  = NKS2 * 400 * 32;   // 166400
  int e = blockIdx.x * 256 + threadIdx.x;
  if (e < CIN_E) {
    int ksg = e >> 12, r = e & 4095, n = r >> 5, kk = r & 31;
    int k = ksg * 32 + kk, h = k & 63, m = k >> 6;
    float v1 = (h < NF) ? w1[(size_t)n * (NF * NF) + h * NF + m] : 0.f;
    float v2 = w2[(size_t)n * (64 * NF) + h * NF + m];
    wp1[e] = (u16)bf16_rne(v1);
    wp2[e] = (u16)bf16_rne(v2);
  } else if (e < CIN_E + D1_E) {
    int e2 = e - CIN_E;
    int ksg = e2 / 12800, r = e2 - ksg * 12800, col = r >> 5, kk = r & 31;
    int k = ksg * 32 + kk;
    wpd1[e2] = (k < IN_DIM) ? (u16)bf16_rne(dw1[(size_t)k * DW + col]) : 0;
  } else if (e < CIN_E + D1_E + D2_E) {
    int e2 = e - CIN_E - D1_E;
    int ksg = e2 / 12800, r = e2 - ksg * 12800, col = r >> 5, kk = r & 31;
    int k = ksg * 32 + kk;
    wpd2[e2] = (k < DW) ? (u16)bf16_rne(dw2[(size_t)k * DW + col]) : 0;
  } else if (e < CIN_E + D1_E + D2_E + 1600) {
    gstat[e - CIN_E - D1_E - D2_E] = 0.f;
  }
}

// ---------------------------------------------------------------------------
// CIN via MFMA, N-split x2 + software-pipelined K-loop.
// Grid (BATCH/16, 2): blockIdx.y picks o-half (64 cols = 4 n-tiles).
// Wave = 4 samples x 4 n-tiles; B-frags double-buffered in registers;
// xv prefetched one m ahead. No LDS, no barriers.
// ---------------------------------------------------------------------------
template <bool LAY2>
__global__ __launch_bounds__(256, 2) void k_cin_mfma(
    const u16* __restrict__ flatb, const u16* __restrict__ nxtg,
    const u16* __restrict__ wp, const float* __restrict__ bias,
    u16* __restrict__ nxt_out, float* __restrict__ res) {
  int t = threadIdx.x;
  int w = t >> 6, lane = t & 63;
  int nl = lane & 15, q = lane >> 4;
  int d = nl;
  int b0 = blockIdx.x * 16 + w * 4;
  int c0 = blockIdx.y * 64;            // o-half base

  // s1 registers: nxr[si][ks][w4] = packed bf16 pair, h = ks*32+q*8+2*w4(+1)
  unsigned nxr[4][2][4];
  if (LAY2) {
#pragma unroll
    for (int si = 0; si < 4; si++)
#pragma unroll
      for (int ks = 0; ks < 2; ks++) {
        uint4 v = *(const uint4*)(nxtg +
            (((size_t)(b0 + si) * 16 + d) * 64 + ks * 32 + q * 8));
        nxr[si][ks][0] = v.x; nxr[si][ks][1] = v.y;
        nxr[si][ks][2] = v.z; nxr[si][ks][3] = v.w;
      }
  } else {
#pragma unroll
    for (int si = 0; si < 4; si++)
#pragma unroll
      for (int ks = 0; ks < 2; ks++)
#pragma unroll
        for (int w4 = 0; w4 < 4; w4++) {
          int h0 = ks * 32 + q * 8 + 2 * w4;
          int h1 = h0 + 1;
          unsigned u0 = (h0 < NF) ? flatb[(size_t)(b0 + si) * AK1 + h0 * 16 + d] : 0;
          unsigned u1 = (h1 < NF) ? flatb[(size_t)(b0 + si) * AK1 + h1 * 16 + d] : 0;
          nxr[si][ks][w4] = u0 | (u1 << 16);
        }
  }

  f32x4 acc[4][4];
#pragma unroll
  for (int si = 0; si < 4; si++)
#pragma unroll
    for (int nt = 0; nt < 4; nt++) acc[si][nt] = (f32x4){0.f, 0.f, 0.f, 0.f};

  const u16* wbase = wp + (size_t)(c0 + nl) * 32 + q * 8;
  short8 bfr[2][4];
#pragma unroll
  for (int nt = 0; nt < 4; nt++)
    bfr[0][nt] = *(const short8*)(wbase + nt * 512);   // ksg = 0

  float xv[4], xvn[4];
#pragma unroll
  for (int si = 0; si < 4; si++)
    xv[si] = bf2f(flatb[(size_t)(b0 + si) * AK1 + d]); // m = 0

  for (int m = 0; m < NF; m++) {
    if (m + 1 < NF) {
#pragma unroll
      for (int si = 0; si < 4; si++)
        xvn[si] = bf2f(flatb[(size_t)(b0 + si) * AK1 + (m + 1) * 16 + d]);
    }
#pragma unroll
    for (int ks = 0; ks < 2; ks++) {
      int ksg = m * 2 + ks;
      int cur = ksg & 1, nxt = cur ^ 1;
      if (ksg + 1 < NKSG) {
        const u16* wb = wbase + (size_t)(ksg + 1) * 4096;
#pragma unroll
        for (int nt = 0; nt < 4; nt++)
          bfr[nxt][nt] = *(const short8*)(wb + nt * 512);
      }
      short8 afr[4];
#pragma unroll
      for (int si = 0; si < 4; si++) {
        union { unsigned u[4]; short8 s; } a;
#pragma unroll
        for (int w4 = 0; w4 < 4; w4++) {
          unsigned u = nxr[si][ks][w4];
          float lo = __uint_as_float(u << 16) * xv[si];
          float hi = __uint_as_float(u & 0xffff0000u) * xv[si];
          a.u[w4] = pack2_trunc(lo, hi);
        }
        afr[si] = a.s;
      }
#pragma unroll
      for (int nt = 0; nt < 4; nt++)
#pragma unroll
        for (int si = 0; si < 4; si++)
          acc[si][nt] = __builtin_amdgcn_mfma_f32_16x16x32_bf16(
              afr[si], bfr[cur][nt], acc[si][nt], 0, 0, 0);
    }
#pragma unroll
    for (int si = 0; si < 4; si++) xv[si] = xvn[si];
  }

  // Epilogue. C layout: col = nl (within n-tile), row d' = q*4 + r.
#pragma unroll
  for (int si = 0; si < 4; si++) {
    int b = b0 + si;
#pragma unroll
    for (int nt = 0; nt < 4; nt++) {
      int o = c0 + nt * 16 + nl;
      float bi = bias[o];
      if (!LAY2 && c0 == 0) {
#pragma unroll
        for (int r = 0; r < 4; r++) {
          float v = fmaxf(acc[si][nt][r] + bi, 0.f);
          nxt_out[((size_t)b * 16 + q * 4 + r) * 64 + o] = (u16)bf16_rne(v);
        }
      } else {
        float s = 0.f;
#pragma unroll
        for (int r = 0; r < 4; r++) s += fmaxf(acc[si][nt][r] + bi, 0.f);
        s += __shfl_xor(s, 16);
        s += __shfl_xor(s, 32);
        if (q == 0) {
          int ri = LAY2 ? (64 + o) : (o - 64);
          res[(size_t)b * 192 + ri] = s;
        }
      }
    }
  }
}

// ---------------------------------------------------------------------------
// Deep-tower GEMM via MFMA with fused BN-stat reduction (unchanged from r3).
// ---------------------------------------------------------------------------
template <bool BN_A, int NKS, int KREAL>
__global__ __launch_bounds__(256) void k_gemm_mfma(
    const u16* __restrict__ Abf, const float* __restrict__ Af32,
    const u16* __restrict__ wp, const float* __restrict__ bias,
    const float* __restrict__ bnS, const float* __restrict__ bnSh,
    float* __restrict__ C, float* __restrict__ gs, float* __restrict__ gs2) {
  __shared__ float ls[160];
  int t = threadIdx.x;
  if (t < 160) ls[t] = 0.f;
  __syncthreads();
  int w = t >> 6, lane = t & 63;
  int nl = lane & 15, q = lane >> 4;
  int row = blockIdx.x * 64 + w * 16 + nl;
  int c0 = blockIdx.y * 80;
  f32x4 acc[5];
#pragma unroll
  for (int nt = 0; nt < 5; nt++) acc[nt] = (f32x4){0.f, 0.f, 0.f, 0.f};

  for (int ksg = 0; ksg < NKS; ksg++) {
    int kb = ksg * 32 + q * 8;
    short8 afr;
    if (!BN_A) {
      afr = *(const short8*)(Abf + (size_t)row * (NKS * 32) + kb);
    } else {
      if (kb + 8 <= KREAL) {
        const float* ap = Af32 + (size_t)row * KREAL + kb;
        float4 f0 = *(const float4*)ap;
        float4 f1 = *(const float4*)(ap + 4);
        union { unsigned u[4]; short8 s; } a;
        float v0 = fmaxf(fmaf(f0.x, bnS[kb + 0], bnSh[kb + 0]), 0.f);
        float v1 = fmaxf(fmaf(f0.y, bnS[kb + 1], bnSh[kb + 1]), 0.f);
        float v2 = fmaxf(fmaf(f0.z, bnS[kb + 2], bnSh[kb + 2]), 0.f);
        float v3 = fmaxf(fmaf(f0.w, bnS[kb + 3], bnSh[kb + 3]), 0.f);
        float v4 = fmaxf(fmaf(f1.x, bnS[kb + 4], bnSh[kb + 4]), 0.f);
        float v5 = fmaxf(fmaf(f1.y, bnS[kb + 5], bnSh[kb + 5]), 0.f);
        float v6 = fmaxf(fmaf(f1.z, bnS[kb + 6], bnSh[kb + 6]), 0.f);
        float v7 = fmaxf(fmaf(f1.w, bnS[kb + 7], bnSh[kb + 7]), 0.f);
        a.u[0] = bf16_rne(v0) | (bf16_rne(v1) << 16);
        a.u[1] = bf16_rne(v2) | (bf16_rne(v3) << 16);
        a.u[2] = bf16_rne(v4) | (bf16_rne(v5) << 16);
        a.u[3] = bf16_rne(v6) | (bf16_rne(v7) << 16);
        afr = a.s;
      } else {
        union { unsigned u[4]; short8 s; } a;
        a.u[0] = a.u[1] = a.u[2] = a.u[3] = 0;
        afr = a.s;
      }
    }
    const u16* wb = wp + (size_t)ksg * (400 * 32) + (size_t)(c0 + nl) * 32 + q * 8;
#pragma unroll
    for (int nt = 0; nt < 5; nt++) {
      short8 bfr = *(const short8*)(wb + nt * 512);
      acc[nt] = __builtin_amdgcn_mfma_f32_16x16x32_bf16(afr, bfr, acc[nt], 0, 0, 0);
    }
  }

  int rbase = blockIdx.x * 64 + w * 16 + q * 4;
#pragma unroll
  for (int nt = 0; nt < 5; nt++) {
    int col = c0 + nt * 16 + nl;
    float bi = bias[col];
    float s = 0.f, s2 = 0.f;
#pragma unroll
    for (int r = 0; r < 4; r++) {
      float v = acc[nt][r] + bi;
      C[(size_t)(rbase + r) * DW + col] = v;
      s += v; s2 = fmaf(v, v, s2);
    }
    s += __shfl_xor(s, 16); s2 += __shfl_xor(s2, 16);
    s += __shfl_xor(s, 32); s2 += __shfl_xor(s2, 32);
    if (q == 0) {
      atomicAdd(&ls[nt * 16 + nl], s);
      atomicAdd(&ls[80 + nt * 16 + nl], s2);
    }
  }
  __syncthreads();
  if (t < 80)       atomicAdd(&gs[c0 + t], ls[t]);
  else if (t < 160) atomicAdd(&gs2[c0 + t - 80], ls[t]);
}

// ---------------------------------------------------------------------------
// BN finalize: (sum, sumsq) -> fused scale/shift
// ---------------------------------------------------------------------------
__global__ __launch_bounds__(256) void k_bnfin(const float* __restrict__ gs,
    const float* __restrict__ gs2, const float* __restrict__ g,
    const float* __restrict__ bt, float* __restrict__ sc, float* __restrict__ sh) {
  int c = blockIdx.x * 256 + threadIdx.x;
  if (c >= DW) return;
  float m = gs[c] * (1.f / BATCH);
  float var = gs2[c] * (1.f / BATCH) - m * m;
  float scl = g[c] * rsqrtf(var + BN_EPS);
  sc[c] = scl;
  sh[c] = bt[c] - m * scl;
}

// ---------------------------------------------------------------------------
// Final concat + dot
// ---------------------------------------------------------------------------
__global__ __launch_bounds__(256) void k_final(const float* __restrict__ lp,
    const float* __restrict__ res, const float* __restrict__ y2,
    const float* __restrict__ sc2, const float* __restrict__ sh2,
    const float* __restrict__ ow, const float* __restrict__ ob,
    float* __restrict__ out) {
  int t = threadIdx.x;
  int lane = t & 63, w = t >> 6;
  int b = blockIdx.x * 4 + w;
  float acc = 0.f;
  for (int j = lane; j < 593; j += 64) {
    float v;
    if (j == 0)       v = lp[b];
    else if (j < 193) v = res[(size_t)b * 192 + (j - 1)];
    else {
      int c = j - 193;
      v = fmaxf(fmaf(y2[(size_t)b * DW + c], sc2[c], sh2[c]), 0.f);
    }
    acc = fmaf(v, ow[j], acc);
  }
#pragma unroll
  for (int k = 1; k < 64; k <<= 1) acc += __shfl_xor(acc, k);
  if (lane == 0) out[b] = acc + ob[0];
}

// ---------------------------------------------------------------------------
extern "C" void kernel_launch(void* const* d_in, const int* in_sizes, int n_in,
                              void* d_out, int out_size, void* d_ws, size_t ws_size,
                              hipStream_t stream) {
  const int*   feat_index = (const int*)d_in[0];
  const float* emb = (const float*)d_in[2];
  const float* lw  = (const float*)d_in[3];
  const float* lb  = (const float*)d_in[4];
  const float* w1  = (const float*)d_in[5];
  const float* b1  = (const float*)d_in[6];
  const float* w2  = (const float*)d_in[7];
  const float* b2  = (const float*)d_in[8];
  const float* dw1 = (const float*)d_in[9];
  const float* db1 = (const float*)d_in[10];
  const float* g1  = (const float*)d_in[11];
  const float* bb1 = (const float*)d_in[12];
  const float* dw2 = (const float*)d_in[13];
  const float* db2 = (const float*)d_in[14];
  const float* g2  = (const float*)d_in[15];
  const float* bb2 = (const float*)d_in[16];
  const float* ow  = (const float*)d_in[17];
  const float* ob  = (const float*)d_in[18];

  float* ws   = (float*)d_ws;
  u16*  flatb = (u16*)ws;                  // 4096*640 bf16 = 1,310,720 f
  float* y1   = ws + 1310720;              // 4096*400 = 1,638,400 f
  float* res  = ws + 2949120;              // 4096*192 =   786,432 f
  float* lp   = ws + 3735552;              // 4096
  float* bn1s = ws + 3739648;              // 400
  float* bn1b = bn1s + 400;
  float* bn2s = bn1b + 400;
  float* bn2b = bn2s + 400;
  float* gA   = ws + 3741248;              // 400 sum
  float* gA2  = gA + 400;                  // 400 sumsq
  float* gB   = gA2 + 400;
  float* gB2  = gB + 400;                  // gstat block: 1600 total (contiguous)
  u16*  nxtg  = (u16*)(ws + 3742848);      // 4096*16*64 bf16 = 2,097,152 f
  float* y2   = ws + 3742848;              // alias nxtg (dead after cin2)
  u16*  wp1   = (u16*)(ws + 5840000);      // 319,488 bf16
  u16*  wp2   = (u16*)(ws + 5999744);
  u16*  wpd1  = (u16*)(ws + 6159488);      // 256,000 bf16
  u16*  wpd2  = (u16*)(ws + 6287488);      // 166,400 bf16 -> 6,370,688 f (25.5 MB)
  float* out  = (float*)d_out;

  const int PREP_E = NKSG * 128 * 32 + NKS1 * 400 * 32 + NKS2 * 400 * 32 + 1600;

  k_gather<<<BATCH, 256, 0, stream>>>(feat_index, emb, lw, lb, flatb, lp);
  k_prep<<<(PREP_E + 255) / 256, 256, 0, stream>>>(w1, w2, dw1, dw2, wp1, wp2,
                                                   wpd1, wpd2, gA);
  k_cin_mfma<false><<<dim3(BATCH / 16, 2), 256, 0, stream>>>(
      flatb, nullptr, wp1, b1, nxtg, res);
  k_cin_mfma<true><<<dim3(BATCH / 16, 2), 256, 0, stream>>>(
      flatb, nxtg, wp2, b2, nullptr, res);
  k_gemm_mfma<false, NKS1, IN_DIM><<<dim3(BATCH / 64, 5), 256, 0, stream>>>(
      flatb, nullptr, wpd1, db1, nullptr, nullptr, y1, gA, gA2);
  k_bnfin<<<2, 256, 0, stream>>>(gA, gA2, g1, bb1, bn1s, bn1b);
  k_gemm_mfma<true, NKS2, DW><<<dim3(BATCH / 64, 5), 256, 0, stream>>>(
      nullptr, y1, wpd2, db2, bn1s, bn1b, y2, gB, gB2);
  k_bnfin<<<2, 256, 0, stream>>>(gB, gB2, g2, bb2, bn2s, bn2b);
  k_final<<<BATCH / 4, 256, 0, stream>>>(lp, res, y2, bn2s, bn2b, ow, ob, out);
}